// Round 5
// baseline (222.423 us; speedup 1.0000x reference)
//
#include <hip/hip_runtime.h>
#include <hip/hip_bf16.h>

#define WINDOW 5
#define DIM 1024
#define FEAT 1024
#define SEQ 128
#define BATCH 128
#define MTOT (BATCH*SEQ)      // 16384
#define NTOT (WINDOW*FEAT)    // 5120
#define KTOT 1024

#define DCHUNK 16             // d-rows per partial-absmax block
#define BUFB 57344            // one dbuf: A 16KB + B 40KB

typedef int int4v __attribute__((ext_vector_type(4)));

static __device__ __forceinline__ unsigned short f2bf(float f) {
  union { float f; unsigned int i; } c; c.f = f;
  unsigned int i = c.i;
  unsigned int lsb = (i >> 16) & 1u;
  i += 0x7fffu + lsb;            // round-to-nearest-even
  return (unsigned short)(i >> 16);
}
static __device__ __forceinline__ float bf2f(unsigned short u) {
  union { unsigned int i; float f; } c; c.i = ((unsigned int)u) << 16; return c.f;
}
static __device__ __forceinline__ signed char q8(float v, float inv) {
  float q = rintf(v * inv);
  q = fminf(fmaxf(q, -127.f), 127.f);
  return (signed char)(int)q;
}

// ---------------- x fp32 -> i8 with per-row scale ----------------
__global__ __launch_bounds__(256) void quant_x(const float* __restrict__ x,
                                               signed char* __restrict__ xq,
                                               float* __restrict__ sx) {
  int row  = blockIdx.x * 4 + (threadIdx.x >> 6);   // one wave per row
  int lane = threadIdx.x & 63;
  const float* xr = x + (size_t)row * KTOT;

  float4 v[4];
  float amax = 0.f;
  #pragma unroll
  for (int i = 0; i < 4; i++) {
    v[i] = ((const float4*)xr)[i * 64 + lane];
    amax = fmaxf(amax, fmaxf(fmaxf(fabsf(v[i].x), fabsf(v[i].y)),
                             fmaxf(fabsf(v[i].z), fabsf(v[i].w))));
  }
  #pragma unroll
  for (int m = 1; m < 64; m <<= 1)
    amax = fmaxf(amax, __shfl_xor(amax, m));

  float inv = amax > 0.f ? 127.f / amax : 0.f;
  int* xqr = (int*)(xq + (size_t)row * KTOT);
  #pragma unroll
  for (int i = 0; i < 4; i++) {
    int p = ((int)(unsigned char)q8(v[i].x, inv)) |
            ((int)(unsigned char)q8(v[i].y, inv) << 8) |
            ((int)(unsigned char)q8(v[i].z, inv) << 16) |
            ((int)q8(v[i].w, inv) << 24);
    xqr[i * 64 + lane] = p;
  }
  if (lane == 0) sx[row] = amax / 127.f;
}

// ---------------- per-(w,f) column absmax, stage 1: coalesced partials ----------------
__global__ __launch_bounds__(256) void w_colamax_part(const float* __restrict__ Ws,
                                                      float* __restrict__ part) {
  int w  = blockIdx.z;
  int dc = blockIdx.y;
  int f4 = threadIdx.x;
  const float* p = Ws + ((size_t)w * DIM + (size_t)dc * DCHUNK) * FEAT;
  float4 m = {0.f, 0.f, 0.f, 0.f};
  #pragma unroll
  for (int d = 0; d < DCHUNK; d++) {
    float4 v = ((const float4*)(p + (size_t)d * FEAT))[f4];
    m.x = fmaxf(m.x, fabsf(v.x));
    m.y = fmaxf(m.y, fabsf(v.y));
    m.z = fmaxf(m.z, fabsf(v.z));
    m.w = fmaxf(m.w, fabsf(v.w));
  }
  ((float4*)(part + ((size_t)w * (DIM / DCHUNK) + dc) * FEAT))[f4] = m;
}

// ---------------- stage 2: fold partials -> sw = amax/127 ----------------
__global__ __launch_bounds__(256) void w_colamax_reduce(const float* __restrict__ part,
                                                        float* __restrict__ sw) {
  int idx = blockIdx.x * 256 + threadIdx.x;   // w*1024 + f, 5120 total
  int w = idx >> 10, f = idx & 1023;
  const float* p = part + (size_t)w * (DIM / DCHUNK) * FEAT + f;
  float m = 0.f;
  #pragma unroll 8
  for (int c = 0; c < DIM / DCHUNK; c++)
    m = fmaxf(m, p[(size_t)c * FEAT]);
  sw[idx] = m / 127.f;
}

// ---------------- Ws[w][d][f] fp32 -> WqT[w][f][d] i8 ----------------
__global__ __launch_bounds__(256) void transq_ws(const float* __restrict__ Ws,
                                                 const float* __restrict__ sw,
                                                 signed char* __restrict__ wq) {
  __shared__ float tile[32][33];
  int w  = blockIdx.z;
  int f0 = blockIdx.x * 32, d0 = blockIdx.y * 32;
  int tx = threadIdx.x, ty = threadIdx.y;       // (32,8)
  const float* src = Ws + ((size_t)w * DIM + d0) * FEAT + f0;
  #pragma unroll
  for (int i = 0; i < 4; i++)
    tile[ty + 8*i][tx] = src[(size_t)(ty + 8*i) * FEAT + tx];
  __syncthreads();
  signed char* dst = wq + ((size_t)w * FEAT + f0) * DIM + d0;
  #pragma unroll
  for (int i = 0; i < 4; i++) {
    int f = f0 + ty + 8*i;
    float swv = sw[(w << 10) + f];
    float inv = swv > 0.f ? 1.0f / swv : 0.f;
    dst[(size_t)(ty + 8*i) * DIM + tx] = q8(tile[tx][ty + 8*i], inv);
  }
}

// ---------------- fused GEMM(i8) + dequant + max-plus scan + tanh ----------------
// 512 thr (8 waves, 2M x 4N), tile = 128 l x 320 c (5w x 64f), BK=128, 8 K-steps.
// Double-buffered LDS (2 x 56KB) + counted-vmcnt pipeline (T3+T4) + setprio (T5).
// Proj tile (80KB bf16, swizzled) unioned over the dbuf region after the K-loop.
__global__ __launch_bounds__(512, 2) void fused_gemm_scan(
    const signed char* __restrict__ xq,   // [MTOT][1024] i8
    const signed char* __restrict__ wq,   // [W*FEAT][1024] i8 (K-contiguous)
    const float* __restrict__ sx,         // [MTOT]
    const float* __restrict__ swp,        // [W*FEAT]
    const float* __restrict__ bias,       // [FEAT]
    float* __restrict__ out)              // [BATCH][FEAT]
{
  __shared__ __align__(16) char smem[2 * BUFB];   // 112 KB

  const int tid  = threadIdx.x;
  const int wid  = tid >> 6;
  const int lane = tid & 63;

  // XCD-chunked swizzle (2048 % 8 == 0 -> bijective); work = b*16 + fslice
  int bid = blockIdx.x;
  int wg  = ((bid & 7) << 8) + (bid >> 3);
  const int b  = wg >> 4;
  const int f0 = (wg & 15) << 6;

  const signed char* aG = xq + (size_t)b * SEQ * KTOT;

  const int wm = wid >> 2, wn = wid & 3;     // wave tile: 64 M x 80 N
  const int rowin = lane >> 3;               // row within 8-row/1KB segment
  const int swb16 = ((lane & 7) ^ rowin) << 4;  // pre-swizzled byte slot in 128B row

  // stage tile kt into buffer at base (As = base, Bs = base+16KB); 7 segs/wave
  #define STAGE(kt_, base_)                                                        \
    do {                                                                           \
      signed char* As_ = (signed char*)(base_);                                    \
      signed char* Bs_ = (signed char*)(base_) + 16384;                            \
      const int k0_ = (kt_) << 7;                                                  \
      _Pragma("unroll")                                                            \
      for (int c_ = 0; c_ < 7; c_++) {                                             \
        int seg_ = wid * 7 + c_;                                                   \
        if (seg_ < 16) {                                                           \
          int row_ = (seg_ << 3) + rowin;                                          \
          __builtin_amdgcn_global_load_lds(                                        \
              (const __attribute__((address_space(1))) void*)(aG + (size_t)row_ * KTOT + k0_ + swb16), \
              (__attribute__((address_space(3))) void*)(As_ + (seg_ << 10)), 16, 0, 0); \
        } else {                                                                   \
          int sb_ = seg_ - 16;                                                     \
          int r_  = (sb_ << 3) + rowin;                                            \
          const signed char* src_ = wq                                             \
              + ((size_t)(((r_ >> 6) << 10) + f0 + (r_ & 63))) * KTOT + k0_ + swb16; \
          __builtin_amdgcn_global_load_lds(                                        \
              (const __attribute__((address_space(1))) void*)src_,                 \
              (__attribute__((address_space(3))) void*)(Bs_ + (sb_ << 10)), 16, 0, 0); \
        }                                                                          \
      }                                                                            \
    } while (0)

  int4v acc[4][5];
  #pragma unroll
  for (int i = 0; i < 4; i++)
    #pragma unroll
    for (int j = 0; j < 5; j++)
      acc[i][j] = (int4v){0, 0, 0, 0};

  STAGE(0, smem);                      // prologue: tile 0 -> buf0

  for (int kt = 0; kt < 8; kt++) {
    char* cur = smem + (size_t)(kt & 1) * BUFB;
    if (kt < 7) {
      STAGE(kt + 1, smem + (size_t)((kt + 1) & 1) * BUFB);
      __builtin_amdgcn_sched_barrier(0);
      asm volatile("s_waitcnt vmcnt(7)" ::: "memory");   // own share of CURRENT tile done
    } else {
      __builtin_amdgcn_sched_barrier(0);
      asm volatile("s_waitcnt vmcnt(0)" ::: "memory");   // last tile: nothing in flight behind
    }
    __builtin_amdgcn_s_barrier();      // all waves certified their pieces
    __builtin_amdgcn_sched_barrier(0);

    const signed char* As = (const signed char*)cur;
    const signed char* Bs = (const signed char*)cur + 16384;
    #pragma unroll
    for (int kk = 0; kk < 2; kk++) {
      int4v a[4], bf[5];
      #pragma unroll
      for (int i = 0; i < 4; i++) {
        int row  = wm * 64 + i * 16 + (lane & 15);
        int slot = (lane >> 4) + (kk << 2);
        a[i] = *(const int4v*)(As + row * 128 + ((slot ^ (row & 7)) << 4));
      }
      #pragma unroll
      for (int j = 0; j < 5; j++) {
        int row  = wn * 80 + j * 16 + (lane & 15);
        int slot = (lane >> 4) + (kk << 2);
        bf[j] = *(const int4v*)(Bs + row * 128 + ((slot ^ (row & 7)) << 4));
      }
      __builtin_amdgcn_s_setprio(1);
      #pragma unroll
      for (int i = 0; i < 4; i++)
        #pragma unroll
        for (int j = 0; j < 5; j++)
          acc[i][j] = __builtin_amdgcn_mfma_i32_16x16x64_i8(a[i], bf[j], acc[i][j], 0, 0, 0);
      __builtin_amdgcn_s_setprio(0);
    }
    __builtin_amdgcn_s_barrier();      // reads of cur done before it is restaged
  }

  __syncthreads();   // full drain: everyone done with LDS before proj overlays it

  // ---- dequant -> bf16 proj tile in LDS [128][320], byte addr ^ ((l>>2)&3)<<5 ----
  float sxv[16];
  #pragma unroll
  for (int i = 0; i < 4; i++)
    #pragma unroll
    for (int r = 0; r < 4; r++)
      sxv[i * 4 + r] = sx[b * SEQ + wm * 64 + i * 16 + ((lane >> 4) << 2) + r];
  float swv[5];
  #pragma unroll
  for (int j = 0; j < 5; j++) {
    int c = wn * 80 + j * 16 + (lane & 15);
    swv[j] = swp[((c >> 6) << 10) + f0 + (c & 63)];
  }

  #pragma unroll
  for (int i = 0; i < 4; i++) {
    #pragma unroll
    for (int j = 0; j < 5; j++) {
      #pragma unroll
      for (int r = 0; r < 4; r++) {
        int l = wm * 64 + i * 16 + ((lane >> 4) << 2) + r;
        int c = wn * 80 + j * 16 + (lane & 15);
        float v = (float)acc[i][j][r] * sxv[i * 4 + r] * swv[j];
        int byte = ((l * 320 + c) << 1) ^ (((l >> 2) & 3) << 5);
        *(unsigned short*)(smem + byte) = f2bf(v);
      }
    }
  }
  __syncthreads();

  // ---- max-plus scan, 5-way state-parallel: thread = (f, k), h_k per thread ----
  {
    const int f = tid >> 3;            // 0..63
    const int k = tid & 7;             // 0..7, active k<5
    float h = 0.f;
    for (int l = 0; l < SEQ; l++) {
      float p = 0.f;
      if (k < 5) {
        int byte = (l * 640 + (((k << 6) + f) << 1)) ^ (((l >> 2) & 3) << 5);
        p = bf2f(*(const unsigned short*)(smem + byte));
      }
      float hprev = __shfl(h, (lane - 1) & 63);   // OLD h_{k-1}
      h = (k == 0) ? fmaxf(p, h) : fmaxf(hprev + p, h);
    }
    if (k == 4)
      out[b * FEAT + f0 + f] = tanhf(h + bias[f0 + f]);
  }
  #undef STAGE
}

extern "C" void kernel_launch(void* const* d_in, const int* in_sizes, int n_in,
                              void* d_out, int out_size, void* d_ws, size_t ws_size,
                              hipStream_t stream) {
  const float* x  = (const float*)d_in[0];
  const float* Ws = (const float*)d_in[1];
  const float* b  = (const float*)d_in[2];
  float* out = (float*)d_out;

  char* ws = (char*)d_ws;
  const size_t XQ_BYTES = (size_t)MTOT * KTOT;                  // 16,777,216
  const size_t WQ_BYTES = (size_t)WINDOW * FEAT * DIM;          //  5,242,880
  const size_t SX_BYTES = (size_t)MTOT * 4;                     //     65,536
  const size_t SW_BYTES = (size_t)WINDOW * FEAT * 4;            //     20,480
  signed char* xq = (signed char*)ws;
  signed char* wq = (signed char*)(ws + XQ_BYTES);
  float* sx   = (float*)(ws + XQ_BYTES + WQ_BYTES);
  float* sw   = (float*)(ws + XQ_BYTES + WQ_BYTES + SX_BYTES);
  float* part = (float*)(ws + XQ_BYTES + WQ_BYTES + SX_BYTES + SW_BYTES);

  hipLaunchKernelGGL(quant_x, dim3(MTOT / 4), dim3(256), 0, stream, x, xq, sx);
  hipLaunchKernelGGL(w_colamax_part, dim3(1, DIM / DCHUNK, WINDOW), dim3(256), 0, stream,
                     Ws, part);
  hipLaunchKernelGGL(w_colamax_reduce, dim3(NTOT / 256), dim3(256), 0, stream, part, sw);
  hipLaunchKernelGGL(transq_ws, dim3(FEAT / 32, DIM / 32, WINDOW), dim3(32, 8), 0, stream,
                     Ws, sw, wq);
  hipLaunchKernelGGL(fused_gemm_scan, dim3(BATCH * 16), dim3(512), 0, stream,
                     xq, wq, sx, sw, b, out);
}